// Round 1
// baseline (511.298 us; speedup 1.0000x reference)
//
#include <hip/hip_runtime.h>
#include <cstdint>
#include <cstddef>

#define B_ 2048
#define N_ 49
#define H_ 1024
#define A_ 512
#define M_ (B_*N_)   // 100352 = 784*128

typedef __attribute__((ext_vector_type(8))) short short8;
typedef __attribute__((ext_vector_type(4))) float f32x4;

__device__ inline unsigned short f2bf(float f){
  union { float f; unsigned u; } v; v.f = f;
  unsigned r = v.u + 0x7FFFu + ((v.u >> 16) & 1u);   // RNE
  return (unsigned short)(r >> 16);
}

__device__ inline float fast_tanh(float x){
  float e = __expf(2.0f*x);
  return 1.0f - 2.0f/(e + 1.0f);
}

// ---------- W (H x A fp32, row-major) -> Wt (A x H bf16) ----------
__global__ __launch_bounds__(256) void k_transpose(
    const float* __restrict__ Wh, const float* __restrict__ Wimg,
    unsigned short* __restrict__ WtH, unsigned short* __restrict__ WtImg){
  const float* src = blockIdx.y ? Wimg : Wh;
  unsigned short* dst = blockIdx.y ? WtImg : WtH;
  int tk = (blockIdx.x & 31) * 32;   // H/32 = 32 k-tiles
  int ta = (blockIdx.x >> 5) * 32;   // A/32 = 16 a-tiles
  __shared__ unsigned short tile[32][33];
  int t = threadIdx.x;
  int r = t >> 3, c4 = t & 7;
  float4 vv = *(const float4*)(src + (size_t)(tk + r)*A_ + ta + c4*4);
  tile[c4*4+0][r] = f2bf(vv.x);
  tile[c4*4+1][r] = f2bf(vv.y);
  tile[c4*4+2][r] = f2bf(vv.z);
  tile[c4*4+3][r] = f2bf(vv.w);
  __syncthreads();
  ushort4 o;
  o.x = tile[r][c4*4+0]; o.y = tile[r][c4*4+1];
  o.z = tile[r][c4*4+2]; o.w = tile[r][c4*4+3];
  *(ushort4*)(dst + (size_t)(ta + r)*H_ + tk + c4*4) = o;
}

// ---------- shared 128x128 MFMA GEMM core (K = H_ = 1024, BK = 64) ----------
#define BK 64
#define LDK 72   // +8 ushort pad (16B) -> conflict-light, keeps 16B alignment

__device__ inline void gemm_tile(const float* __restrict__ Asrc,
                                 const unsigned short* __restrict__ Wt,
                                 int m0, int a0, f32x4 acc[4][4],
                                 unsigned short (*sA)[LDK], unsigned short (*sB)[LDK]){
  const int t = threadIdx.x;
  const int l = t & 63, w = t >> 6;
  const int wr = w >> 1, wc = w & 1;
  const int g = l >> 4, c = l & 15;
  #pragma unroll
  for (int m=0;m<4;m++)
    #pragma unroll
    for (int n=0;n<4;n++)
      acc[m][n] = f32x4{0.f,0.f,0.f,0.f};

  for (int k0 = 0; k0 < H_; k0 += BK){
    // stage A: 128 x 64 fp32 -> bf16 (coalesced float4, RNE convert, b64 LDS writes)
    #pragma unroll
    for (int i=0;i<8;i++){
      int f = i*256 + t;
      int row = f >> 4, c4 = f & 15;
      float4 vv = *(const float4*)(Asrc + (size_t)(m0+row)*H_ + k0 + c4*4);
      ushort4 h; h.x=f2bf(vv.x); h.y=f2bf(vv.y); h.z=f2bf(vv.z); h.w=f2bf(vv.w);
      *(ushort4*)&sA[row][c4*4] = h;
    }
    // stage B from pre-transposed bf16 Wt: rows a0..a0+127, cols k0..k0+63
    #pragma unroll
    for (int i=0;i<8;i++){
      int f = i*256 + t;
      int row = f >> 4, c4 = f & 15;
      *(ushort4*)&sB[row][c4*4] = *(const ushort4*)(Wt + (size_t)(a0+row)*H_ + k0 + c4*4);
    }
    __syncthreads();
    #pragma unroll
    for (int kk=0; kk<BK; kk+=32){
      short8 aF[4], bF[4];
      #pragma unroll
      for (int m=0;m<4;m++) aF[m] = *(const short8*)&sA[wr*64 + m*16 + c][kk + g*8];
      #pragma unroll
      for (int n=0;n<4;n++) bF[n] = *(const short8*)&sB[wc*64 + n*16 + c][kk + g*8];
      #pragma unroll
      for (int m=0;m<4;m++)
        #pragma unroll
        for (int n=0;n<4;n++)
          acc[m][n] = __builtin_amdgcn_mfma_f32_16x16x32_bf16(aF[m], bF[n], acc[m][n], 0, 0, 0);
    }
    __syncthreads();
  }
}

// ---------- h_proj = hidden @ W_h + b_h ----------
__global__ __launch_bounds__(256) void k_hproj(
    const float* __restrict__ hidden, const unsigned short* __restrict__ WtH,
    const float* __restrict__ b_h, float* __restrict__ hproj){
  __shared__ __align__(16) unsigned short sA[128][LDK];
  __shared__ __align__(16) unsigned short sB[128][LDK];
  f32x4 acc[4][4];
  int m0 = blockIdx.x * 128, a0 = blockIdx.y * 128;
  gemm_tile(hidden, WtH, m0, a0, acc, sA, sB);
  const int l = threadIdx.x & 63, w = threadIdx.x >> 6;
  const int wr = w >> 1, wc = w & 1, g = l >> 4, c = l & 15;
  #pragma unroll
  for (int n=0;n<4;n++){
    int col = a0 + wc*64 + n*16 + c;
    float bh = b_h[col];
    #pragma unroll
    for (int m=0;m<4;m++)
      #pragma unroll
      for (int r=0;r<4;r++){
        int rowg = m0 + wr*64 + m*16 + g*4 + r;
        hproj[(size_t)rowg*A_ + col] = acc[m][n][r] + bh;
      }
  }
}

// ---------- scores: tanh(h_proj + img@W_img + b_img + cov*W_cov) . v ----------
__global__ __launch_bounds__(256) void k_scores(
    const float* __restrict__ img, const unsigned short* __restrict__ WtImg,
    const float* __restrict__ hproj, const float* __restrict__ b_img,
    const float* __restrict__ cov, const float* __restrict__ Wcov,
    const float* __restrict__ v, float* __restrict__ scores){
  __shared__ __align__(16) unsigned short sA[128][LDK];
  __shared__ __align__(16) unsigned short sB[128][LDK];
  __shared__ float sH[4][128];
  f32x4 acc[4][4];
  int m0 = blockIdx.x * 128, a0 = blockIdx.y * 128;
  gemm_tile(img, WtImg, m0, a0, acc, sA, sB);
  // stage the <=4 distinct h_proj rows this block's 128 output rows touch
  int bFirst = m0 / N_;
  int bLast  = (m0 + 127) / N_;
  int nB = bLast - bFirst + 1;
  for (int idx = threadIdx.x; idx < nB*128; idx += 256){
    int bb = idx >> 7, a = idx & 127;
    sH[bb][a] = hproj[(size_t)(bFirst + bb)*A_ + a0 + a];
  }
  __syncthreads();
  const int l = threadIdx.x & 63, w = threadIdx.x >> 6;
  const int wr = w >> 1, wc = w & 1, g = l >> 4, c = l & 15;
  float vv[4], bi[4], wcv[4];
  #pragma unroll
  for (int n=0;n<4;n++){
    int col = a0 + wc*64 + n*16 + c;
    vv[n] = v[col]; bi[n] = b_img[col]; wcv[n] = Wcov[col];
  }
  #pragma unroll
  for (int m=0;m<4;m++)
    #pragma unroll
    for (int r=0;r<4;r++){
      int rowg = m0 + wr*64 + m*16 + g*4 + r;
      int bb = rowg / N_;              // row -> batch
      float cv = cov[rowg];            // coverage is (B,N) flat == rowg
      float s = 0.f;
      #pragma unroll
      for (int n=0;n<4;n++){
        float x = acc[m][n][r] + sH[bb - bFirst][wc*64 + n*16 + c] + bi[n] + cv*wcv[n];
        s += fast_tanh(x) * vv[n];
      }
      // reduce over the 16 lanes holding this row's 16 columns
      s += __shfl_xor(s, 1, 16);
      s += __shfl_xor(s, 2, 16);
      s += __shfl_xor(s, 4, 16);
      s += __shfl_xor(s, 8, 16);
      if (c == 0) atomicAdd(&scores[rowg], s);
    }
}

// ---------- softmax over N + context = alpha . img ----------
__global__ __launch_bounds__(256) void k_ctx(
    const float* __restrict__ img, const float* __restrict__ scores,
    float* __restrict__ outCtx, float* __restrict__ outAlpha){
  int b = blockIdx.x;
  __shared__ float sAl[N_];
  int t = threadIdx.x;
  if (t < 64){
    float s = (t < N_) ? scores[b*N_ + t] : -1e30f;
    float m = s;
    #pragma unroll
    for (int off=32; off>=1; off>>=1) m = fmaxf(m, __shfl_xor(m, off));
    float e = (t < N_) ? __expf(s - m) : 0.f;
    float sum = e;
    #pragma unroll
    for (int off=32; off>=1; off>>=1) sum += __shfl_xor(sum, off);
    float al = e / sum;
    if (t < N_){ sAl[t] = al; outAlpha[b*N_ + t] = al; }
  }
  __syncthreads();
  const float4* ib = (const float4*)(img + (size_t)b*N_*H_);
  float4 acc = {0.f,0.f,0.f,0.f};
  for (int n=0;n<N_;n++){
    float al = sAl[n];
    float4 x = ib[n*(H_/4) + t];
    acc.x += al*x.x; acc.y += al*x.y; acc.z += al*x.z; acc.w += al*x.w;
  }
  *(float4*)(outCtx + (size_t)b*H_ + t*4) = acc;
}

extern "C" void kernel_launch(void* const* d_in, const int* in_sizes, int n_in,
                              void* d_out, int out_size, void* d_ws, size_t ws_size,
                              hipStream_t stream){
  const float* hidden = (const float*)d_in[0];
  const float* img    = (const float*)d_in[1];
  const float* cov    = (const float*)d_in[2];
  const float* W_h    = (const float*)d_in[3];
  const float* b_h    = (const float*)d_in[4];
  const float* W_img  = (const float*)d_in[5];
  const float* b_img  = (const float*)d_in[6];
  const float* W_cov  = (const float*)d_in[7];
  const float* v      = (const float*)d_in[8];

  char* ws = (char*)d_ws;
  unsigned short* WtH   = (unsigned short*)ws;               // 1 MB
  unsigned short* WtImg = (unsigned short*)(ws + (1u<<20));  // 1 MB
  float* hproj  = (float*)(ws + (2u<<20));                   // 4 MB
  float* scores = (float*)(ws + (6u<<20));                   // 0.4 MB

  float* outCtx   = (float*)d_out;
  float* outAlpha = outCtx + (size_t)B_*H_;

  hipMemsetAsync(scores, 0, (size_t)M_*sizeof(float), stream);
  k_transpose<<<dim3(512, 2), 256, 0, stream>>>(W_h, W_img, WtH, WtImg);
  k_hproj<<<dim3(B_/128, A_/128), 256, 0, stream>>>(hidden, WtH, b_h, hproj);
  k_scores<<<dim3(M_/128, A_/128), 256, 0, stream>>>(img, WtImg, hproj, b_img, cov, W_cov, v, scores);
  k_ctx<<<B_, 256, 0, stream>>>(img, scores, outCtx, outAlpha);
}

// Round 2
// 414.116 us; speedup vs baseline: 1.2347x; 1.2347x over previous
//
#include <hip/hip_runtime.h>
#include <cstdint>
#include <cstddef>

#define B_ 2048
#define N_ 49
#define H_ 1024
#define A_ 512
#define M_ (B_*N_)   // 100352 = 784*128

typedef __attribute__((ext_vector_type(8))) short short8;
typedef __attribute__((ext_vector_type(8))) unsigned short ushort8;
typedef __attribute__((ext_vector_type(4))) float f32x4;
typedef unsigned int u32;

__device__ inline unsigned short f2bf(float f){
  union { float f; unsigned u; } v; v.f = f;
  unsigned r = v.u + 0x7FFFu + ((v.u >> 16) & 1u);   // RNE
  return (unsigned short)(r >> 16);
}
__device__ inline float bf2f(unsigned short h){
  union { u32 u; float f; } v; v.u = ((u32)h) << 16; return v.f;
}
__device__ inline float fast_tanh(float x){
  float e = __expf(2.0f*x);
  return 1.0f - 2.0f/(e + 1.0f);
}
__device__ inline void gl16(const void* g, void* l){
  __builtin_amdgcn_global_load_lds((const __attribute__((address_space(1))) u32*)g,
                                   (__attribute__((address_space(3))) u32*)l, 16, 0, 0);
}

// ---------- W (H x A fp32, row-major) -> Wt (A x H bf16) ----------
__global__ __launch_bounds__(256) void k_transpose(
    const float* __restrict__ Wh, const float* __restrict__ Wimg,
    unsigned short* __restrict__ WtH, unsigned short* __restrict__ WtImg){
  const float* src = blockIdx.y ? Wimg : Wh;
  unsigned short* dst = blockIdx.y ? WtImg : WtH;
  int tk = (blockIdx.x & 31) * 32;
  int ta = (blockIdx.x >> 5) * 32;
  __shared__ unsigned short tile[32][33];
  int t = threadIdx.x;
  int r = t >> 3, c4 = t & 7;
  float4 vv = *(const float4*)(src + (size_t)(tk + r)*A_ + ta + c4*4);
  tile[c4*4+0][r] = f2bf(vv.x);
  tile[c4*4+1][r] = f2bf(vv.y);
  tile[c4*4+2][r] = f2bf(vv.z);
  tile[c4*4+3][r] = f2bf(vv.w);
  __syncthreads();
  ushort4 o;
  o.x = tile[r][c4*4+0]; o.y = tile[r][c4*4+1];
  o.z = tile[r][c4*4+2]; o.w = tile[r][c4*4+3];
  *(ushort4*)(dst + (size_t)(ta + r)*H_ + tk + c4*4) = o;
}

// ---------- img fp32 -> bf16 (grid-stride, 32B in / 16B out per thread) ----------
__global__ __launch_bounds__(256) void k_convert(
    const float* __restrict__ src, unsigned short* __restrict__ dst, size_t n8){
  size_t i = (size_t)blockIdx.x*256 + threadIdx.x;
  size_t stride = (size_t)gridDim.x*256;
  const float4* s4 = (const float4*)src;
  ushort8* d8 = (ushort8*)dst;
  for (; i < n8; i += stride){
    float4 a = s4[2*i], b = s4[2*i+1];
    ushort8 o;
    o[0]=f2bf(a.x); o[1]=f2bf(a.y); o[2]=f2bf(a.z); o[3]=f2bf(a.w);
    o[4]=f2bf(b.x); o[5]=f2bf(b.y); o[6]=f2bf(b.z); o[7]=f2bf(b.w);
    d8[i] = o;
  }
}

// ================= fallback-path GEMM (round-1, fp32 A staging) =================
#define BK 64
#define LDK 72

__device__ inline void gemm_tile(const float* __restrict__ Asrc,
                                 const unsigned short* __restrict__ Wt,
                                 int m0, int a0, f32x4 acc[4][4],
                                 unsigned short (*sA)[LDK], unsigned short (*sB)[LDK]){
  const int t = threadIdx.x;
  const int l = t & 63, w = t >> 6;
  const int wr = w >> 1, wc = w & 1;
  const int g = l >> 4, c = l & 15;
  #pragma unroll
  for (int m=0;m<4;m++)
    #pragma unroll
    for (int n=0;n<4;n++)
      acc[m][n] = f32x4{0.f,0.f,0.f,0.f};

  for (int k0 = 0; k0 < H_; k0 += BK){
    #pragma unroll
    for (int i=0;i<8;i++){
      int f = i*256 + t;
      int row = f >> 4, c4 = f & 15;
      float4 vv = *(const float4*)(Asrc + (size_t)(m0+row)*H_ + k0 + c4*4);
      ushort4 h; h.x=f2bf(vv.x); h.y=f2bf(vv.y); h.z=f2bf(vv.z); h.w=f2bf(vv.w);
      *(ushort4*)&sA[row][c4*4] = h;
    }
    #pragma unroll
    for (int i=0;i<8;i++){
      int f = i*256 + t;
      int row = f >> 4, c4 = f & 15;
      *(ushort4*)&sB[row][c4*4] = *(const ushort4*)(Wt + (size_t)(a0+row)*H_ + k0 + c4*4);
    }
    __syncthreads();
    #pragma unroll
    for (int kk=0; kk<BK; kk+=32){
      short8 aF[4], bF[4];
      #pragma unroll
      for (int m=0;m<4;m++) aF[m] = *(const short8*)&sA[wr*64 + m*16 + c][kk + g*8];
      #pragma unroll
      for (int n=0;n<4;n++) bF[n] = *(const short8*)&sB[wc*64 + n*16 + c][kk + g*8];
      #pragma unroll
      for (int m=0;m<4;m++)
        #pragma unroll
        for (int n=0;n<4;n++)
          acc[m][n] = __builtin_amdgcn_mfma_f32_16x16x32_bf16(aF[m], bF[n], acc[m][n], 0, 0, 0);
    }
    __syncthreads();
  }
}

// ---------- h_proj = hidden @ W_h + b_h (fp32-staged; small) ----------
__global__ __launch_bounds__(256) void k_hproj(
    const float* __restrict__ hidden, const unsigned short* __restrict__ WtH,
    const float* __restrict__ b_h, float* __restrict__ hproj){
  __shared__ __align__(16) unsigned short sA[128][LDK];
  __shared__ __align__(16) unsigned short sB[128][LDK];
  f32x4 acc[4][4];
  int m0 = blockIdx.x * 128, a0 = blockIdx.y * 128;
  gemm_tile(hidden, WtH, m0, a0, acc, sA, sB);
  const int l = threadIdx.x & 63, w = threadIdx.x >> 6;
  const int wr = w >> 1, wc = w & 1, g = l >> 4, c = l & 15;
  #pragma unroll
  for (int n=0;n<4;n++){
    int col = a0 + wc*64 + n*16 + c;
    float bh = b_h[col];
    #pragma unroll
    for (int m=0;m<4;m++)
      #pragma unroll
      for (int r=0;r<4;r++){
        int rowg = m0 + wr*64 + m*16 + g*4 + r;
        hproj[(size_t)rowg*A_ + col] = acc[m][n][r] + bh;
      }
  }
}

// ================= fast-path score GEMM: bf16 A via global_load_lds =================
__global__ __launch_bounds__(256) void k_scores_b(
    const unsigned short* __restrict__ Ab, const unsigned short* __restrict__ Wt,
    const float* __restrict__ hproj, const float* __restrict__ b_img,
    const float* __restrict__ cov, const float* __restrict__ Wcov,
    const float* __restrict__ v, float* __restrict__ scoresP){
  __shared__ __align__(16) unsigned short sA[128][64];
  __shared__ __align__(16) unsigned short sB[128][64];
  __shared__ float sH[4][128];
  __shared__ float sS[128];
  const int t = threadIdx.x;
  const int l = t & 63, w = t >> 6;
  const int wr = w >> 1, wc = w & 1;
  const int g = l >> 4, c = l & 15;

  // bijective XCD-chunked swizzle: consecutive wg (same m-panel, 4 a0 blocks)
  // land on the same XCD close in time -> A-panel L2 reuse.
  const int nwg = (M_/128)*(A_/128);      // 3136, %8==0
  int bid = blockIdx.x;
  int wg = (bid & 7) * (nwg/8) + (bid >> 3);
  int m0 = (wg >> 2) * 128;
  int a0 = (wg & 3) * 128;

  // global_load_lds staging geometry: wave w covers rows [w*32, w*32+32),
  // chunk cc covers rows +cc*8; lane l -> row +(l>>3), col (l&7)*8 ushorts.
  const int srow = w*32 + (l >> 3);
  const int scol = (l & 7) * 8;
  const unsigned short* gA = Ab + (size_t)(m0 + srow)*H_ + scol;
  const unsigned short* gB = Wt + (size_t)(a0 + srow)*H_ + scol;
  char* lA = (char*)sA + w*4096;
  char* lB = (char*)sB + w*4096;

  f32x4 acc[4][4];
  #pragma unroll
  for (int m=0;m<4;m++)
    #pragma unroll
    for (int n=0;n<4;n++)
      acc[m][n] = f32x4{0.f,0.f,0.f,0.f};

  for (int k0 = 0; k0 < H_; k0 += 64){
    #pragma unroll
    for (int cc=0; cc<4; cc++){
      gl16(gA + (size_t)cc*8*H_ + k0, lA + cc*1024);
      gl16(gB + (size_t)cc*8*H_ + k0, lB + cc*1024);
    }
    __syncthreads();
    #pragma unroll
    for (int kk=0; kk<64; kk+=32){
      short8 aF[4], bF[4];
      #pragma unroll
      for (int m=0;m<4;m++) aF[m] = *(const short8*)&sA[wr*64 + m*16 + c][kk + g*8];
      #pragma unroll
      for (int n=0;n<4;n++) bF[n] = *(const short8*)&sB[wc*64 + n*16 + c][kk + g*8];
      #pragma unroll
      for (int m=0;m<4;m++)
        #pragma unroll
        for (int n=0;n<4;n++)
          acc[m][n] = __builtin_amdgcn_mfma_f32_16x16x32_bf16(aF[m], bF[n], acc[m][n], 0, 0, 0);
    }
    __syncthreads();
  }

  // epilogue: stage h_proj rows, zero score accumulator
  int bFirst = m0 / N_;
  int bLast  = (m0 + 127) / N_;
  int nB = bLast - bFirst + 1;
  if (t < 128) sS[t] = 0.f;
  for (int idx = t; idx < nB*128; idx += 256){
    int bb = idx >> 7, a = idx & 127;
    sH[bb][a] = hproj[(size_t)(bFirst + bb)*A_ + a0 + a];
  }
  __syncthreads();

  float vv[4], bi[4], wcv[4];
  #pragma unroll
  for (int n=0;n<4;n++){
    int col = a0 + wc*64 + n*16 + c;
    vv[n] = v[col]; bi[n] = b_img[col]; wcv[n] = Wcov[col];
  }
  #pragma unroll
  for (int m=0;m<4;m++)
    #pragma unroll
    for (int r=0;r<4;r++){
      int rowl = wr*64 + m*16 + g*4 + r;
      int rowg = m0 + rowl;
      int bb = rowg / N_;
      float cv = cov[rowg];
      float s = 0.f;
      #pragma unroll
      for (int n=0;n<4;n++){
        float x = acc[m][n][r] + sH[bb - bFirst][wc*64 + n*16 + c] + bi[n] + cv*wcv[n];
        s += fast_tanh(x) * vv[n];
      }
      s += __shfl_xor(s, 1, 16);
      s += __shfl_xor(s, 2, 16);
      s += __shfl_xor(s, 4, 16);
      s += __shfl_xor(s, 8, 16);
      if (c == 0) atomicAdd(&sS[rowl], s);
    }
  __syncthreads();
  if (t < 128) scoresP[(size_t)(a0 >> 7)*M_ + m0 + t] = sS[t];
}

// ---------- fallback score GEMM (round-1, atomics into scores) ----------
__global__ __launch_bounds__(256) void k_scores_f(
    const float* __restrict__ img, const unsigned short* __restrict__ WtImg,
    const float* __restrict__ hproj, const float* __restrict__ b_img,
    const float* __restrict__ cov, const float* __restrict__ Wcov,
    const float* __restrict__ v, float* __restrict__ scores){
  __shared__ __align__(16) unsigned short sA[128][LDK];
  __shared__ __align__(16) unsigned short sB[128][LDK];
  __shared__ float sH[4][128];
  f32x4 acc[4][4];
  int m0 = blockIdx.x * 128, a0 = blockIdx.y * 128;
  gemm_tile(img, WtImg, m0, a0, acc, sA, sB);
  int bFirst = m0 / N_;
  int bLast  = (m0 + 127) / N_;
  int nB = bLast - bFirst + 1;
  for (int idx = threadIdx.x; idx < nB*128; idx += 256){
    int bb = idx >> 7, a = idx & 127;
    sH[bb][a] = hproj[(size_t)(bFirst + bb)*A_ + a0 + a];
  }
  __syncthreads();
  const int l = threadIdx.x & 63, w = threadIdx.x >> 6;
  const int wr = w >> 1, wc = w & 1, g = l >> 4, c = l & 15;
  float vv[4], bi[4], wcv[4];
  #pragma unroll
  for (int n=0;n<4;n++){
    int col = a0 + wc*64 + n*16 + c;
    vv[n] = v[col]; bi[n] = b_img[col]; wcv[n] = Wcov[col];
  }
  #pragma unroll
  for (int m=0;m<4;m++)
    #pragma unroll
    for (int r=0;r<4;r++){
      int rowg = m0 + wr*64 + m*16 + g*4 + r;
      int bb = rowg / N_;
      float cv = cov[rowg];
      float s = 0.f;
      #pragma unroll
      for (int n=0;n<4;n++){
        float x = acc[m][n][r] + sH[bb - bFirst][wc*64 + n*16 + c] + bi[n] + cv*wcv[n];
        s += fast_tanh(x) * vv[n];
      }
      s += __shfl_xor(s, 1, 16);
      s += __shfl_xor(s, 2, 16);
      s += __shfl_xor(s, 4, 16);
      s += __shfl_xor(s, 8, 16);
      if (c == 0) atomicAdd(&scores[rowg], s);
    }
}

// ---------- softmax + context, bf16 img (fast path) ----------
__global__ __launch_bounds__(256) void k_ctx_b(
    const unsigned short* __restrict__ imgb, const float* __restrict__ scoresP,
    float* __restrict__ outCtx, float* __restrict__ outAlpha){
  int b = blockIdx.x;
  __shared__ float sAl[N_];
  int t = threadIdx.x;
  if (t < 64){
    float s = -1e30f;
    if (t < N_){
      size_t rg = (size_t)b*N_ + t;
      s = scoresP[rg] + scoresP[M_ + rg] + scoresP[2*(size_t)M_ + rg] + scoresP[3*(size_t)M_ + rg];
    }
    float m = s;
    #pragma unroll
    for (int off=32; off>=1; off>>=1) m = fmaxf(m, __shfl_xor(m, off));
    float e = (t < N_) ? __expf(s - m) : 0.f;
    float sum = e;
    #pragma unroll
    for (int off=32; off>=1; off>>=1) sum += __shfl_xor(sum, off);
    float al = e / sum;
    if (t < N_){ sAl[t] = al; outAlpha[(size_t)b*N_ + t] = al; }
  }
  __syncthreads();
  float4 acc = {0.f,0.f,0.f,0.f};
  #pragma unroll 7
  for (int n=0;n<N_;n++){
    float al = sAl[n];
    ushort4 x = *(const ushort4*)(imgb + ((size_t)b*N_ + n)*H_ + t*4);
    acc.x += al*bf2f(x.x); acc.y += al*bf2f(x.y);
    acc.z += al*bf2f(x.z); acc.w += al*bf2f(x.w);
  }
  *(float4*)(outCtx + (size_t)b*H_ + t*4) = acc;
}

// ---------- fallback softmax + context, fp32 img ----------
__global__ __launch_bounds__(256) void k_ctx_f(
    const float* __restrict__ img, const float* __restrict__ scores,
    float* __restrict__ outCtx, float* __restrict__ outAlpha){
  int b = blockIdx.x;
  __shared__ float sAl[N_];
  int t = threadIdx.x;
  if (t < 64){
    float s = (t < N_) ? scores[(size_t)b*N_ + t] : -1e30f;
    float m = s;
    #pragma unroll
    for (int off=32; off>=1; off>>=1) m = fmaxf(m, __shfl_xor(m, off));
    float e = (t < N_) ? __expf(s - m) : 0.f;
    float sum = e;
    #pragma unroll
    for (int off=32; off>=1; off>>=1) sum += __shfl_xor(sum, off);
    float al = e / sum;
    if (t < N_){ sAl[t] = al; outAlpha[(size_t)b*N_ + t] = al; }
  }
  __syncthreads();
  const float4* ib = (const float4*)(img + (size_t)b*N_*H_);
  float4 acc = {0.f,0.f,0.f,0.f};
  for (int n=0;n<N_;n++){
    float al = sAl[n];
    float4 x = ib[n*(H_/4) + t];
    acc.x += al*x.x; acc.y += al*x.y; acc.z += al*x.z; acc.w += al*x.w;
  }
  *(float4*)(outCtx + (size_t)b*H_ + t*4) = acc;
}

extern "C" void kernel_launch(void* const* d_in, const int* in_sizes, int n_in,
                              void* d_out, int out_size, void* d_ws, size_t ws_size,
                              hipStream_t stream){
  const float* hidden = (const float*)d_in[0];
  const float* img    = (const float*)d_in[1];
  const float* cov    = (const float*)d_in[2];
  const float* W_h    = (const float*)d_in[3];
  const float* b_h    = (const float*)d_in[4];
  const float* W_img  = (const float*)d_in[5];
  const float* b_img  = (const float*)d_in[6];
  const float* W_cov  = (const float*)d_in[7];
  const float* v      = (const float*)d_in[8];

  char* ws = (char*)d_ws;
  unsigned short* WtH   = (unsigned short*)ws;               // 1 MB
  unsigned short* WtImg = (unsigned short*)(ws + (1u<<20));  // 1 MB
  float* hproj   = (float*)(ws + (2u<<20));                  // 4 MB
  float* scoresP = (float*)(ws + (6u<<20));                  // 1.6 MB (4 slabs) / scores
  unsigned short* imgb = (unsigned short*)(ws + (8u<<20));   // 196 MB

  float* outCtx   = (float*)d_out;
  float* outAlpha = outCtx + (size_t)B_*H_;

  const size_t needed = (8ull<<20) + (size_t)M_*H_*2;

  k_transpose<<<dim3(512, 2), 256, 0, stream>>>(W_h, W_img, WtH, WtImg);
  k_hproj<<<dim3(B_/128, A_/128), 256, 0, stream>>>(hidden, WtH, b_h, hproj);

  if (ws_size >= needed){
    k_convert<<<2048, 256, 0, stream>>>(img, imgb, (size_t)M_*H_/8);
    k_scores_b<<<(M_/128)*(A_/128), 256, 0, stream>>>(imgb, WtImg, hproj, b_img, cov, W_cov, v, scoresP);
    k_ctx_b<<<B_, 256, 0, stream>>>(imgb, scoresP, outCtx, outAlpha);
  } else {
    hipMemsetAsync(scoresP, 0, (size_t)M_*sizeof(float), stream);
    k_scores_f<<<dim3(M_/128, A_/128), 256, 0, stream>>>(img, WtImg, hproj, b_img, cov, W_cov, v, scoresP);
    k_ctx_f<<<B_, 256, 0, stream>>>(img, scoresP, outCtx, outAlpha);
  }
}

// Round 3
// 381.863 us; speedup vs baseline: 1.3390x; 1.0845x over previous
//
#include <hip/hip_runtime.h>
#include <cstdint>
#include <cstddef>

#define B_ 2048
#define N_ 49
#define H_ 1024
#define A_ 512
#define M_ (B_*N_)   // 100352 = 392*256

typedef __attribute__((ext_vector_type(8))) short short8;
typedef __attribute__((ext_vector_type(8))) unsigned short ushort8;
typedef __attribute__((ext_vector_type(4))) float f32x4;
typedef unsigned int u32;

__device__ inline unsigned short f2bf(float f){
  union { float f; unsigned u; } v; v.f = f;
  unsigned r = v.u + 0x7FFFu + ((v.u >> 16) & 1u);   // RNE
  return (unsigned short)(r >> 16);
}
__device__ inline float bf2f(unsigned short h){
  union { u32 u; float f; } v; v.u = ((u32)h) << 16; return v.f;
}
__device__ inline float fast_tanh(float x){
  float e = __expf(2.0f*x);
  return 1.0f - 2.0f/(e + 1.0f);
}
__device__ inline void gl16(const void* g, void* l){
  __builtin_amdgcn_global_load_lds((const __attribute__((address_space(1))) u32*)g,
                                   (__attribute__((address_space(3))) u32*)l, 16, 0, 0);
}

// ---------- W (H x A fp32, row-major) -> Wt (A x H bf16) ----------
__global__ __launch_bounds__(256) void k_transpose(
    const float* __restrict__ Wh, const float* __restrict__ Wimg,
    unsigned short* __restrict__ WtH, unsigned short* __restrict__ WtImg){
  const float* src = blockIdx.y ? Wimg : Wh;
  unsigned short* dst = blockIdx.y ? WtImg : WtH;
  int tk = (blockIdx.x & 31) * 32;
  int ta = (blockIdx.x >> 5) * 32;
  __shared__ unsigned short tile[32][33];
  int t = threadIdx.x;
  int r = t >> 3, c4 = t & 7;
  float4 vv = *(const float4*)(src + (size_t)(tk + r)*A_ + ta + c4*4);
  tile[c4*4+0][r] = f2bf(vv.x);
  tile[c4*4+1][r] = f2bf(vv.y);
  tile[c4*4+2][r] = f2bf(vv.z);
  tile[c4*4+3][r] = f2bf(vv.w);
  __syncthreads();
  ushort4 o;
  o.x = tile[r][c4*4+0]; o.y = tile[r][c4*4+1];
  o.z = tile[r][c4*4+2]; o.w = tile[r][c4*4+3];
  *(ushort4*)(dst + (size_t)(ta + r)*H_ + tk + c4*4) = o;
}

// ---------- img fp32 -> bf16 ----------
__global__ __launch_bounds__(256) void k_convert(
    const float* __restrict__ src, unsigned short* __restrict__ dst, size_t n8){
  size_t i = (size_t)blockIdx.x*256 + threadIdx.x;
  size_t stride = (size_t)gridDim.x*256;
  const float4* s4 = (const float4*)src;
  ushort8* d8 = (ushort8*)dst;
  for (; i < n8; i += stride){
    float4 a = s4[2*i], b = s4[2*i+1];
    ushort8 o;
    o[0]=f2bf(a.x); o[1]=f2bf(a.y); o[2]=f2bf(a.z); o[3]=f2bf(a.w);
    o[4]=f2bf(b.x); o[5]=f2bf(b.y); o[6]=f2bf(b.z); o[7]=f2bf(b.w);
    d8[i] = o;
  }
}

// ================= fallback GEMM core (round-1) =================
#define BK 64
#define LDK 72

__device__ inline void gemm_tile(const float* __restrict__ Asrc,
                                 const unsigned short* __restrict__ Wt,
                                 int m0, int a0, f32x4 acc[4][4],
                                 unsigned short (*sA)[LDK], unsigned short (*sB)[LDK]){
  const int t = threadIdx.x;
  const int l = t & 63, w = t >> 6;
  const int wr = w >> 1, wc = w & 1;
  const int g = l >> 4, c = l & 15;
  #pragma unroll
  for (int m=0;m<4;m++)
    #pragma unroll
    for (int n=0;n<4;n++)
      acc[m][n] = f32x4{0.f,0.f,0.f,0.f};

  for (int k0 = 0; k0 < H_; k0 += BK){
    #pragma unroll
    for (int i=0;i<8;i++){
      int f = i*256 + t;
      int row = f >> 4, c4 = f & 15;
      float4 vv = *(const float4*)(Asrc + (size_t)(m0+row)*H_ + k0 + c4*4);
      ushort4 h; h.x=f2bf(vv.x); h.y=f2bf(vv.y); h.z=f2bf(vv.z); h.w=f2bf(vv.w);
      *(ushort4*)&sA[row][c4*4] = h;
    }
    #pragma unroll
    for (int i=0;i<8;i++){
      int f = i*256 + t;
      int row = f >> 4, c4 = f & 15;
      *(ushort4*)&sB[row][c4*4] = *(const ushort4*)(Wt + (size_t)(a0+row)*H_ + k0 + c4*4);
    }
    __syncthreads();
    #pragma unroll
    for (int kk=0; kk<BK; kk+=32){
      short8 aF[4], bF[4];
      #pragma unroll
      for (int m=0;m<4;m++) aF[m] = *(const short8*)&sA[wr*64 + m*16 + c][kk + g*8];
      #pragma unroll
      for (int n=0;n<4;n++) bF[n] = *(const short8*)&sB[wc*64 + n*16 + c][kk + g*8];
      #pragma unroll
      for (int m=0;m<4;m++)
        #pragma unroll
        for (int n=0;n<4;n++)
          acc[m][n] = __builtin_amdgcn_mfma_f32_16x16x32_bf16(aF[m], bF[n], acc[m][n], 0, 0, 0);
    }
    __syncthreads();
  }
}

// ---------- h_proj = hidden @ W_h + b_h ----------
__global__ __launch_bounds__(256) void k_hproj(
    const float* __restrict__ hidden, const unsigned short* __restrict__ WtH,
    const float* __restrict__ b_h, float* __restrict__ hproj){
  __shared__ __align__(16) unsigned short sA[128][LDK];
  __shared__ __align__(16) unsigned short sB[128][LDK];
  f32x4 acc[4][4];
  int m0 = blockIdx.x * 128, a0 = blockIdx.y * 128;
  gemm_tile(hidden, WtH, m0, a0, acc, sA, sB);
  const int l = threadIdx.x & 63, w = threadIdx.x >> 6;
  const int wr = w >> 1, wc = w & 1, g = l >> 4, c = l & 15;
  #pragma unroll
  for (int n=0;n<4;n++){
    int col = a0 + wc*64 + n*16 + c;
    float bh = b_h[col];
    #pragma unroll
    for (int m=0;m<4;m++)
      #pragma unroll
      for (int r=0;r<4;r++){
        int rowg = m0 + wr*64 + m*16 + g*4 + r;
        hproj[(size_t)rowg*A_ + col] = acc[m][n][r] + bh;
      }
  }
}

// ============ fast path: 256x256 / BK=64 / 8-wave / 8-phase-style GEMM ============
// LDS: dbuf x { A[2 halves][128][64], B[2 halves][128][64] } bf16 = 128 KiB.
// XOR swizzle byte ^= ((row&7)<<4) applied on LDS *reads*; global source is
// pre-swizzled per-lane so global_load_lds' linear write lands swizzled data.
__global__ __launch_bounds__(512, 2) void k_scores_b8(
    const unsigned short* __restrict__ Ab, const unsigned short* __restrict__ Wt,
    const float* __restrict__ hproj, const float* __restrict__ b_img,
    const float* __restrict__ cov, const float* __restrict__ Wcov,
    const float* __restrict__ v, float* __restrict__ scoresP){
  __shared__ __align__(16) char lds[131072];
  const int t = threadIdx.x;
  const int l = t & 63, w = t >> 6;       // 8 waves
  const int wr = w >> 2, wc = w & 3;      // 2 (M) x 4 (N)
  const int g = l >> 4, c = l & 15;
  const int cm = (c & 7) << 4;            // read-side XOR swizzle

  // bijective XCD-chunked swizzle; consecutive wg pairs share the A-panel.
  const int nwg = (M_/256)*(A_/256);      // 784, %8==0
  int bid = blockIdx.x;
  int wg = (bid & 7)*(nwg/8) + (bid >> 3);
  const int m0 = (wg >> 1) * 256;
  const int a0 = (wg & 1) * 256;

  // staging: wave w stages rows [w*16, w*16+16) of each 128-row half,
  // as 2 chunks of 8 rows; lane l -> row +(l>>3), k-offset pre-swizzled.
  const int rsub = l >> 3;
  const int ksw  = ((l & 7) ^ rsub) * 8;  // elements

  f32x4 acc[8][4] = {};

  auto stage = [&](int bn, int k0){
    #pragma unroll
    for (int h=0; h<2; h++){
      #pragma unroll
      for (int q=0; q<2; q++){
        int dA = bn*65536 + h*16384 + w*2048 + q*1024;
        const unsigned short* ga = Ab + (size_t)(m0 + h*128 + w*16 + q*8 + rsub)*H_ + k0 + ksw;
        const unsigned short* gb = Wt + (size_t)(a0 + h*128 + w*16 + q*8 + rsub)*H_ + k0 + ksw;
        gl16(ga, lds + dA);
        gl16(gb, lds + dA + 32768);
      }
    }
  };

  const int abase = wr*16384;                  // my A half
  const int bbase = 32768 + (wc>>1)*16384;     // my B half
  const int brow  = (wc&1)*64;

  stage(0, 0);
  for (int tt=0; tt<16; tt++){
    const int cur = (tt & 1) << 16;
    if (tt < 15){
      stage((tt+1)&1, (tt+1)*64);
      asm volatile("s_waitcnt vmcnt(8)" ::: "memory"); // my tile-tt loads done
    } else {
      asm volatile("s_waitcnt vmcnt(0)" ::: "memory");
    }
    asm volatile("s_barrier" ::: "memory");            // everyone's done
    #pragma unroll
    for (int p=0; p<4; p++){
      const int mh  = p >> 1;
      const int kb  = (p & 1) * 64;                    // kk byte base
      short8 aF[4], bF[4];
      #pragma unroll
      for (int i=0;i<4;i++){
        int rl = (mh*4+i)*16 + c;
        aF[i] = *(const short8*)(lds + cur + abase + rl*128 + ((kb + g*16) ^ cm));
      }
      #pragma unroll
      for (int n=0;n<4;n++){
        int rb = brow + n*16 + c;
        bF[n] = *(const short8*)(lds + cur + bbase + rb*128 + ((kb + g*16) ^ cm));
      }
      asm volatile("s_barrier" ::: "memory");
      __builtin_amdgcn_s_setprio(1);
      #pragma unroll
      for (int i=0;i<4;i++)
        #pragma unroll
        for (int n=0;n<4;n++)
          acc[mh*4+i][n] = __builtin_amdgcn_mfma_f32_16x16x32_bf16(aF[i], bF[n], acc[mh*4+i][n], 0, 0, 0);
      __builtin_amdgcn_s_setprio(0);
      asm volatile("s_barrier" ::: "memory");
    }
  }

  // ---------------- epilogue: tanh + v-dot + row-reduce ----------------
  float* sS = (float*)lds;            // [256]
  float* sH = (float*)lds + 256;      // [nB][256], nB<=7
  const int bFirst = m0 / N_;
  const int nB = (m0 + 255)/N_ - bFirst + 1;
  if (t < 256) sS[t] = 0.f;
  for (int idx = t; idx < nB*256; idx += 512){
    int bb = idx >> 8, a = idx & 255;
    sH[bb*256 + a] = hproj[(size_t)(bFirst + bb)*A_ + a0 + a];
  }
  __syncthreads();

  float vv[4], bi[4], wcv[4];
  #pragma unroll
  for (int n=0;n<4;n++){
    int colg = a0 + wc*64 + n*16 + c;
    vv[n] = v[colg]; bi[n] = b_img[colg]; wcv[n] = Wcov[colg];
  }
  #pragma unroll
  for (int m=0;m<8;m++){
    #pragma unroll
    for (int r=0;r<4;r++){
      int rowl = wr*128 + m*16 + g*4 + r;
      int rowg = m0 + rowl;
      int bb = rowg / N_ - bFirst;
      float cv = cov[rowg];
      float s = 0.f;
      #pragma unroll
      for (int n=0;n<4;n++){
        float x = acc[m][n][r] + sH[bb*256 + wc*64 + n*16 + c] + bi[n] + cv*wcv[n];
        s += fast_tanh(x) * vv[n];
      }
      s += __shfl_xor(s, 1, 16);
      s += __shfl_xor(s, 2, 16);
      s += __shfl_xor(s, 4, 16);
      s += __shfl_xor(s, 8, 16);
      if (c == 0) atomicAdd(&sS[rowl], s);
    }
  }
  __syncthreads();
  if (t < 256) scoresP[(size_t)(a0 >> 8)*M_ + m0 + t] = sS[t];
}

// ---------- fallback score GEMM (round-1) ----------
__global__ __launch_bounds__(256) void k_scores_f(
    const float* __restrict__ img, const unsigned short* __restrict__ WtImg,
    const float* __restrict__ hproj, const float* __restrict__ b_img,
    const float* __restrict__ cov, const float* __restrict__ Wcov,
    const float* __restrict__ v, float* __restrict__ scores){
  __shared__ __align__(16) unsigned short sA[128][LDK];
  __shared__ __align__(16) unsigned short sB[128][LDK];
  __shared__ float sH[4][128];
  f32x4 acc[4][4];
  int m0 = blockIdx.x * 128, a0 = blockIdx.y * 128;
  gemm_tile(img, WtImg, m0, a0, acc, sA, sB);
  int bFirst = m0 / N_;
  int bLast  = (m0 + 127) / N_;
  int nB = bLast - bFirst + 1;
  for (int idx = threadIdx.x; idx < nB*128; idx += 256){
    int bb = idx >> 7, a = idx & 127;
    sH[bb][a] = hproj[(size_t)(bFirst + bb)*A_ + a0 + a];
  }
  __syncthreads();
  const int l = threadIdx.x & 63, w = threadIdx.x >> 6;
  const int wr = w >> 1, wc = w & 1, g = l >> 4, c = l & 15;
  float vv[4], bi[4], wcv[4];
  #pragma unroll
  for (int n=0;n<4;n++){
    int col = a0 + wc*64 + n*16 + c;
    vv[n] = v[col]; bi[n] = b_img[col]; wcv[n] = Wcov[col];
  }
  #pragma unroll
  for (int m=0;m<4;m++)
    #pragma unroll
    for (int r=0;r<4;r++){
      int rowg = m0 + wr*64 + m*16 + g*4 + r;
      int bb = rowg / N_;
      float cv = cov[rowg];
      float s = 0.f;
      #pragma unroll
      for (int n=0;n<4;n++){
        float x = acc[m][n][r] + sH[bb - bFirst][wc*64 + n*16 + c] + bi[n] + cv*wcv[n];
        s += fast_tanh(x) * vv[n];
      }
      s += __shfl_xor(s, 1, 16);
      s += __shfl_xor(s, 2, 16);
      s += __shfl_xor(s, 4, 16);
      s += __shfl_xor(s, 8, 16);
      if (c == 0) atomicAdd(&scores[rowg], s);
    }
}

// ---------- softmax + context, bf16 img (fast path, 2 slabs) ----------
__global__ __launch_bounds__(256) void k_ctx_b(
    const unsigned short* __restrict__ imgb, const float* __restrict__ scoresP,
    float* __restrict__ outCtx, float* __restrict__ outAlpha){
  int b = blockIdx.x;
  __shared__ float sAl[N_];
  int t = threadIdx.x;
  if (t < 64){
    float s = -1e30f;
    if (t < N_){
      size_t rg = (size_t)b*N_ + t;
      s = scoresP[rg] + scoresP[(size_t)M_ + rg];
    }
    float m = s;
    #pragma unroll
    for (int off=32; off>=1; off>>=1) m = fmaxf(m, __shfl_xor(m, off));
    float e = (t < N_) ? __expf(s - m) : 0.f;
    float sum = e;
    #pragma unroll
    for (int off=32; off>=1; off>>=1) sum += __shfl_xor(sum, off);
    float al = e / sum;
    if (t < N_){ sAl[t] = al; outAlpha[(size_t)b*N_ + t] = al; }
  }
  __syncthreads();
  float4 acc = {0.f,0.f,0.f,0.f};
  #pragma unroll 7
  for (int n=0;n<N_;n++){
    float al = sAl[n];
    ushort4 x = *(const ushort4*)(imgb + ((size_t)b*N_ + n)*H_ + t*4);
    acc.x += al*bf2f(x.x); acc.y += al*bf2f(x.y);
    acc.z += al*bf2f(x.z); acc.w += al*bf2f(x.w);
  }
  *(float4*)(outCtx + (size_t)b*H_ + t*4) = acc;
}

// ---------- fallback softmax + context ----------
__global__ __launch_bounds__(256) void k_ctx_f(
    const float* __restrict__ img, const float* __restrict__ scores,
    float* __restrict__ outCtx, float* __restrict__ outAlpha){
  int b = blockIdx.x;
  __shared__ float sAl[N_];
  int t = threadIdx.x;
  if (t < 64){
    float s = (t < N_) ? scores[(size_t)b*N_ + t] : -1e30f;
    float m = s;
    #pragma unroll
    for (int off=32; off>=1; off>>=1) m = fmaxf(m, __shfl_xor(m, off));
    float e = (t < N_) ? __expf(s - m) : 0.f;
    float sum = e;
    #pragma unroll
    for (int off=32; off>=1; off>>=1) sum += __shfl_xor(sum, off);
    float al = e / sum;
    if (t < N_){ sAl[t] = al; outAlpha[(size_t)b*N_ + t] = al; }
  }
  __syncthreads();
  const float4* ib = (const float4*)(img + (size_t)b*N_*H_);
  float4 acc = {0.f,0.f,0.f,0.f};
  for (int n=0;n<N_;n++){
    float al = sAl[n];
    float4 x = ib[n*(H_/4) + t];
    acc.x += al*x.x; acc.y += al*x.y; acc.z += al*x.z; acc.w += al*x.w;
  }
  *(float4*)(outCtx + (size_t)b*H_ + t*4) = acc;
}

extern "C" void kernel_launch(void* const* d_in, const int* in_sizes, int n_in,
                              void* d_out, int out_size, void* d_ws, size_t ws_size,
                              hipStream_t stream){
  const float* hidden = (const float*)d_in[0];
  const float* img    = (const float*)d_in[1];
  const float* cov    = (const float*)d_in[2];
  const float* W_h    = (const float*)d_in[3];
  const float* b_h    = (const float*)d_in[4];
  const float* W_img  = (const float*)d_in[5];
  const float* b_img  = (const float*)d_in[6];
  const float* W_cov  = (const float*)d_in[7];
  const float* v      = (const float*)d_in[8];

  char* ws = (char*)d_ws;
  unsigned short* WtH   = (unsigned short*)ws;               // 1 MB
  unsigned short* WtImg = (unsigned short*)(ws + (1u<<20));  // 1 MB
  float* hproj   = (float*)(ws + (2u<<20));                  // 4 MB
  float* scoresP = (float*)(ws + (6u<<20));                  // 2 slabs (0.8 MB) / scores
  unsigned short* imgb = (unsigned short*)(ws + (8u<<20));   // 196 MB

  float* outCtx   = (float*)d_out;
  float* outAlpha = outCtx + (size_t)B_*H_;

  const size_t needed = (8ull<<20) + (size_t)M_*H_*2;

  k_transpose<<<dim3(512, 2), 256, 0, stream>>>(W_h, W_img, WtH, WtImg);
  k_hproj<<<dim3(B_/128, A_/128), 256, 0, stream>>>(hidden, WtH, b_h, hproj);

  if (ws_size >= needed){
    k_convert<<<2048, 256, 0, stream>>>(img, imgb, (size_t)M_*H_/8);
    k_scores_b8<<<(M_/256)*(A_/256), 512, 0, stream>>>(imgb, WtImg, hproj, b_img, cov, W_cov, v, scoresP);
    k_ctx_b<<<B_, 256, 0, stream>>>(imgb, scoresP, outCtx, outAlpha);
  } else {
    hipMemsetAsync(scoresP, 0, (size_t)M_*sizeof(float), stream);
    k_scores_f<<<dim3(M_/128, A_/128), 256, 0, stream>>>(img, WtImg, hproj, b_img, cov, W_cov, v, scoresP);
    k_ctx_f<<<B_, 256, 0, stream>>>(img, scoresP, outCtx, outAlpha);
  }
}

// Round 4
// 371.378 us; speedup vs baseline: 1.3768x; 1.0282x over previous
//
#include <hip/hip_runtime.h>
#include <cstdint>
#include <cstddef>

#define B_ 2048
#define N_ 49
#define H_ 1024
#define A_ 512
#define M_ (B_*N_)   // 100352 = 392*256

typedef __attribute__((ext_vector_type(8))) short short8;
typedef __attribute__((ext_vector_type(8))) unsigned short ushort8;
typedef __attribute__((ext_vector_type(4))) float f32x4;
typedef unsigned int u32;

__device__ inline unsigned short f2bf(float f){
  union { float f; unsigned u; } v; v.f = f;
  unsigned r = v.u + 0x7FFFu + ((v.u >> 16) & 1u);   // RNE
  return (unsigned short)(r >> 16);
}
__device__ inline float bf2f(unsigned short h){
  union { u32 u; float f; } v; v.u = ((u32)h) << 16; return v.f;
}
__device__ inline float fast_tanh(float x){
  float e = __expf(2.0f*x);
  return 1.0f - 2.0f/(e + 1.0f);
}
__device__ inline void gl16(const void* g, void* l){
  __builtin_amdgcn_global_load_lds((const __attribute__((address_space(1))) u32*)g,
                                   (__attribute__((address_space(3))) u32*)l, 16, 0, 0);
}

// ---------- W (H x A fp32, row-major) -> Wt (A x H bf16) ----------
__global__ __launch_bounds__(256) void k_transpose(
    const float* __restrict__ Wh, const float* __restrict__ Wimg,
    unsigned short* __restrict__ WtH, unsigned short* __restrict__ WtImg){
  const float* src = blockIdx.y ? Wimg : Wh;
  unsigned short* dst = blockIdx.y ? WtImg : WtH;
  int tk = (blockIdx.x & 31) * 32;
  int ta = (blockIdx.x >> 5) * 32;
  __shared__ unsigned short tile[32][33];
  int t = threadIdx.x;
  int r = t >> 3, c4 = t & 7;
  float4 vv = *(const float4*)(src + (size_t)(tk + r)*A_ + ta + c4*4);
  tile[c4*4+0][r] = f2bf(vv.x);
  tile[c4*4+1][r] = f2bf(vv.y);
  tile[c4*4+2][r] = f2bf(vv.z);
  tile[c4*4+3][r] = f2bf(vv.w);
  __syncthreads();
  ushort4 o;
  o.x = tile[r][c4*4+0]; o.y = tile[r][c4*4+1];
  o.z = tile[r][c4*4+2]; o.w = tile[r][c4*4+3];
  *(ushort4*)(dst + (size_t)(ta + r)*H_ + tk + c4*4) = o;
}

// ---------- img fp32 -> bf16 ----------
__global__ __launch_bounds__(256) void k_convert(
    const float* __restrict__ src, unsigned short* __restrict__ dst, size_t n8){
  size_t i = (size_t)blockIdx.x*256 + threadIdx.x;
  size_t stride = (size_t)gridDim.x*256;
  const float4* s4 = (const float4*)src;
  ushort8* d8 = (ushort8*)dst;
  for (; i < n8; i += stride){
    float4 a = s4[2*i], b = s4[2*i+1];
    ushort8 o;
    o[0]=f2bf(a.x); o[1]=f2bf(a.y); o[2]=f2bf(a.z); o[3]=f2bf(a.w);
    o[4]=f2bf(b.x); o[5]=f2bf(b.y); o[6]=f2bf(b.z); o[7]=f2bf(b.w);
    d8[i] = o;
  }
}

// ================= fallback GEMM core (round-1) =================
#define BK 64
#define LDK 72

__device__ inline void gemm_tile(const float* __restrict__ Asrc,
                                 const unsigned short* __restrict__ Wt,
                                 int m0, int a0, f32x4 acc[4][4],
                                 unsigned short (*sA)[LDK], unsigned short (*sB)[LDK]){
  const int t = threadIdx.x;
  const int l = t & 63, w = t >> 6;
  const int wr = w >> 1, wc = w & 1;
  const int g = l >> 4, c = l & 15;
  #pragma unroll
  for (int m=0;m<4;m++)
    #pragma unroll
    for (int n=0;n<4;n++)
      acc[m][n] = f32x4{0.f,0.f,0.f,0.f};

  for (int k0 = 0; k0 < H_; k0 += BK){
    #pragma unroll
    for (int i=0;i<8;i++){
      int f = i*256 + t;
      int row = f >> 4, c4 = f & 15;
      float4 vv = *(const float4*)(Asrc + (size_t)(m0+row)*H_ + k0 + c4*4);
      ushort4 h; h.x=f2bf(vv.x); h.y=f2bf(vv.y); h.z=f2bf(vv.z); h.w=f2bf(vv.w);
      *(ushort4*)&sA[row][c4*4] = h;
    }
    #pragma unroll
    for (int i=0;i<8;i++){
      int f = i*256 + t;
      int row = f >> 4, c4 = f & 15;
      *(ushort4*)&sB[row][c4*4] = *(const ushort4*)(Wt + (size_t)(a0+row)*H_ + k0 + c4*4);
    }
    __syncthreads();
    #pragma unroll
    for (int kk=0; kk<BK; kk+=32){
      short8 aF[4], bF[4];
      #pragma unroll
      for (int m=0;m<4;m++) aF[m] = *(const short8*)&sA[wr*64 + m*16 + c][kk + g*8];
      #pragma unroll
      for (int n=0;n<4;n++) bF[n] = *(const short8*)&sB[wc*64 + n*16 + c][kk + g*8];
      #pragma unroll
      for (int m=0;m<4;m++)
        #pragma unroll
        for (int n=0;n<4;n++)
          acc[m][n] = __builtin_amdgcn_mfma_f32_16x16x32_bf16(aF[m], bF[n], acc[m][n], 0, 0, 0);
    }
    __syncthreads();
  }
}

// ---------- h_proj = hidden @ W_h + b_h ----------
__global__ __launch_bounds__(256) void k_hproj(
    const float* __restrict__ hidden, const unsigned short* __restrict__ WtH,
    const float* __restrict__ b_h, float* __restrict__ hproj){
  __shared__ __align__(16) unsigned short sA[128][LDK];
  __shared__ __align__(16) unsigned short sB[128][LDK];
  f32x4 acc[4][4];
  int m0 = blockIdx.x * 128, a0 = blockIdx.y * 128;
  gemm_tile(hidden, WtH, m0, a0, acc, sA, sB);
  const int l = threadIdx.x & 63, w = threadIdx.x >> 6;
  const int wr = w >> 1, wc = w & 1, g = l >> 4, c = l & 15;
  #pragma unroll
  for (int n=0;n<4;n++){
    int col = a0 + wc*64 + n*16 + c;
    float bh = b_h[col];
    #pragma unroll
    for (int m=0;m<4;m++)
      #pragma unroll
      for (int r=0;r<4;r++){
        int rowg = m0 + wr*64 + m*16 + g*4 + r;
        hproj[(size_t)rowg*A_ + col] = acc[m][n][r] + bh;
      }
  }
}

// ============ fast path: 256x256 / BK=64 / 8-wave / 2-barrier counted-vmcnt ============
// LDS: dbuf x { A[256][64], B[256][64] } bf16 = 128 KiB.
// XOR swizzle byte ^= ((row&7)<<4) on LDS reads; global source pre-swizzled
// per-lane so global_load_lds' linear write lands swizzled data (rule 21).
// Sync per K-step: stage(next) -> vmcnt(8) [prev step's 8 loads, issued a
// full step ago, are the only older outstanding ops] -> barrier -> 4 MFMA
// clusters (no internal barriers; read-read sharing is safe) -> barrier
// [all reads of buf[cur] done before next step stages into buf[cur^1]'s
// parity partner two steps out].
__global__ __launch_bounds__(512, 2) void k_scores_b2p(
    const unsigned short* __restrict__ Ab, const unsigned short* __restrict__ Wt,
    const float* __restrict__ hproj, const float* __restrict__ b_img,
    const float* __restrict__ cov, const float* __restrict__ Wcov,
    const float* __restrict__ v, float* __restrict__ scoresP){
  __shared__ __align__(16) char lds[131072];
  const int t = threadIdx.x;
  const int l = t & 63, w = t >> 6;       // 8 waves
  const int wr = w >> 2, wc = w & 3;      // 2 (M) x 4 (N)
  const int g = l >> 4, c = l & 15;
  const int cm = (c & 7) << 4;            // read-side XOR swizzle

  // bijective XCD-chunked swizzle; consecutive wg pairs share the A-panel.
  const int nwg = (M_/256)*(A_/256);      // 784, %8==0
  int bid = blockIdx.x;
  int wg = (bid & 7)*(nwg/8) + (bid >> 3);
  const int m0 = (wg >> 1) * 256;
  const int a0 = (wg & 1) * 256;

  // staging: wave w stages rows [w*16, w*16+16) of each 128-row half,
  // as 2 chunks of 8 rows; lane l -> row +(l>>3), k-offset pre-swizzled.
  const int rsub = l >> 3;
  const int ksw  = ((l & 7) ^ rsub) * 8;  // elements

  f32x4 acc[8][4] = {};

  auto stage = [&](int bn, int k0){
    #pragma unroll
    for (int h=0; h<2; h++){
      #pragma unroll
      for (int q=0; q<2; q++){
        int dA = bn*65536 + h*16384 + w*2048 + q*1024;
        const unsigned short* ga = Ab + (size_t)(m0 + h*128 + w*16 + q*8 + rsub)*H_ + k0 + ksw;
        const unsigned short* gb = Wt + (size_t)(a0 + h*128 + w*16 + q*8 + rsub)*H_ + k0 + ksw;
        gl16(ga, lds + dA);
        gl16(gb, lds + dA + 32768);
      }
    }
  };

  const int abase = wr*16384;                  // my A half
  const int bbase = 32768 + (wc>>1)*16384;     // my B half
  const int brow  = (wc&1)*64;

  stage(0, 0);
  for (int tt=0; tt<16; tt++){
    const int cur = (tt & 1) << 16;
    if (tt < 15){
      stage((tt+1)&1, (tt+1)*64);
      asm volatile("s_waitcnt vmcnt(8)" ::: "memory"); // tile-tt loads done (mine)
    } else {
      asm volatile("s_waitcnt vmcnt(0)" ::: "memory");
    }
    asm volatile("s_barrier" ::: "memory");            // everyone's loads done
    #pragma unroll
    for (int p=0; p<4; p++){
      const int mh  = p >> 1;
      const int kb  = (p & 1) * 64;                    // kk byte base
      short8 aF[4], bF[4];
      #pragma unroll
      for (int i=0;i<4;i++){
        int rl = (mh*4+i)*16 + c;
        aF[i] = *(const short8*)(lds + cur + abase + rl*128 + ((kb + g*16) ^ cm));
      }
      #pragma unroll
      for (int n=0;n<4;n++){
        int rb = brow + n*16 + c;
        bF[n] = *(const short8*)(lds + cur + bbase + rb*128 + ((kb + g*16) ^ cm));
      }
      __builtin_amdgcn_s_setprio(1);
      #pragma unroll
      for (int i=0;i<4;i++)
        #pragma unroll
        for (int n=0;n<4;n++)
          acc[mh*4+i][n] = __builtin_amdgcn_mfma_f32_16x16x32_bf16(aF[i], bF[n], acc[mh*4+i][n], 0, 0, 0);
      __builtin_amdgcn_s_setprio(0);
    }
    asm volatile("s_barrier" ::: "memory");            // reads of buf[cur] done
  }

  // ---------------- epilogue: tanh + v-dot + row-reduce ----------------
  float* sS = (float*)lds;            // [256]
  float* sH = (float*)lds + 256;      // [nB][256], nB<=7
  const int bFirst = m0 / N_;
  const int nB = (m0 + 255)/N_ - bFirst + 1;
  if (t < 256) sS[t] = 0.f;
  for (int idx = t; idx < nB*256; idx += 512){
    int bb = idx >> 8, a = idx & 255;
    sH[bb*256 + a] = hproj[(size_t)(bFirst + bb)*A_ + a0 + a];
  }
  __syncthreads();

  float vv[4], bi[4], wcv[4];
  #pragma unroll
  for (int n=0;n<4;n++){
    int colg = a0 + wc*64 + n*16 + c;
    vv[n] = v[colg]; bi[n] = b_img[colg]; wcv[n] = Wcov[colg];
  }
  #pragma unroll
  for (int m=0;m<8;m++){
    #pragma unroll
    for (int r=0;r<4;r++){
      int rowl = wr*128 + m*16 + g*4 + r;
      int rowg = m0 + rowl;
      int bb = rowg / N_ - bFirst;
      float cv = cov[rowg];
      float s = 0.f;
      #pragma unroll
      for (int n=0;n<4;n++){
        float x = acc[m][n][r] + sH[bb*256 + wc*64 + n*16 + c] + bi[n] + cv*wcv[n];
        s += fast_tanh(x) * vv[n];
      }
      s += __shfl_xor(s, 1, 16);
      s += __shfl_xor(s, 2, 16);
      s += __shfl_xor(s, 4, 16);
      s += __shfl_xor(s, 8, 16);
      if (c == 0) atomicAdd(&sS[rowl], s);
    }
  }
  __syncthreads();
  if (t < 256) scoresP[(size_t)(a0 >> 8)*M_ + m0 + t] = sS[t];
}

// ---------- fallback score GEMM (round-1) ----------
__global__ __launch_bounds__(256) void k_scores_f(
    const float* __restrict__ img, const unsigned short* __restrict__ WtImg,
    const float* __restrict__ hproj, const float* __restrict__ b_img,
    const float* __restrict__ cov, const float* __restrict__ Wcov,
    const float* __restrict__ v, float* __restrict__ scores){
  __shared__ __align__(16) unsigned short sA[128][LDK];
  __shared__ __align__(16) unsigned short sB[128][LDK];
  __shared__ float sH[4][128];
  f32x4 acc[4][4];
  int m0 = blockIdx.x * 128, a0 = blockIdx.y * 128;
  gemm_tile(img, WtImg, m0, a0, acc, sA, sB);
  int bFirst = m0 / N_;
  int bLast  = (m0 + 127) / N_;
  int nB = bLast - bFirst + 1;
  for (int idx = threadIdx.x; idx < nB*128; idx += 256){
    int bb = idx >> 7, a = idx & 127;
    sH[bb][a] = hproj[(size_t)(bFirst + bb)*A_ + a0 + a];
  }
  __syncthreads();
  const int l = threadIdx.x & 63, w = threadIdx.x >> 6;
  const int wr = w >> 1, wc = w & 1, g = l >> 4, c = l & 15;
  float vv[4], bi[4], wcv[4];
  #pragma unroll
  for (int n=0;n<4;n++){
    int col = a0 + wc*64 + n*16 + c;
    vv[n] = v[col]; bi[n] = b_img[col]; wcv[n] = Wcov[col];
  }
  #pragma unroll
  for (int m=0;m<4;m++)
    #pragma unroll
    for (int r=0;r<4;r++){
      int rowg = m0 + wr*64 + m*16 + g*4 + r;
      int bb = rowg / N_;
      float cv = cov[rowg];
      float s = 0.f;
      #pragma unroll
      for (int n=0;n<4;n++){
        float x = acc[m][n][r] + sH[bb - bFirst][wc*64 + n*16 + c] + bi[n] + cv*wcv[n];
        s += fast_tanh(x) * vv[n];
      }
      s += __shfl_xor(s, 1, 16);
      s += __shfl_xor(s, 2, 16);
      s += __shfl_xor(s, 4, 16);
      s += __shfl_xor(s, 8, 16);
      if (c == 0) atomicAdd(&scores[rowg], s);
    }
}

// ---------- softmax + context, bf16 img (fast path, 2 slabs) ----------
__global__ __launch_bounds__(256) void k_ctx_b(
    const unsigned short* __restrict__ imgb, const float* __restrict__ scoresP,
    float* __restrict__ outCtx, float* __restrict__ outAlpha){
  int b = blockIdx.x;
  __shared__ float sAl[N_];
  int t = threadIdx.x;
  if (t < 64){
    float s = -1e30f;
    if (t < N_){
      size_t rg = (size_t)b*N_ + t;
      s = scoresP[rg] + scoresP[(size_t)M_ + rg];
    }
    float m = s;
    #pragma unroll
    for (int off=32; off>=1; off>>=1) m = fmaxf(m, __shfl_xor(m, off));
    float e = (t < N_) ? __expf(s - m) : 0.f;
    float sum = e;
    #pragma unroll
    for (int off=32; off>=1; off>>=1) sum += __shfl_xor(sum, off);
    float al = e / sum;
    if (t < N_){ sAl[t] = al; outAlpha[(size_t)b*N_ + t] = al; }
  }
  __syncthreads();
  float4 acc = {0.f,0.f,0.f,0.f};
  #pragma unroll 7
  for (int n=0;n<N_;n++){
    float al = sAl[n];
    ushort4 x = *(const ushort4*)(imgb + ((size_t)b*N_ + n)*H_ + t*4);
    acc.x += al*bf2f(x.x); acc.y += al*bf2f(x.y);
    acc.z += al*bf2f(x.z); acc.w += al*bf2f(x.w);
  }
  *(float4*)(outCtx + (size_t)b*H_ + t*4) = acc;
}

// ---------- fallback softmax + context ----------
__global__ __launch_bounds__(256) void k_ctx_f(
    const float* __restrict__ img, const float* __restrict__ scores,
    float* __restrict__ outCtx, float* __restrict__ outAlpha){
  int b = blockIdx.x;
  __shared__ float sAl[N_];
  int t = threadIdx.x;
  if (t < 64){
    float s = (t < N_) ? scores[(size_t)b*N_ + t] : -1e30f;
    float m = s;
    #pragma unroll
    for (int off=32; off>=1; off>>=1) m = fmaxf(m, __shfl_xor(m, off));
    float e = (t < N_) ? __expf(s - m) : 0.f;
    float sum = e;
    #pragma unroll
    for (int off=32; off>=1; off>>=1) sum += __shfl_xor(sum, off);
    float al = e / sum;
    if (t < N_){ sAl[t] = al; outAlpha[(size_t)b*N_ + t] = al; }
  }
  __syncthreads();
  const float4* ib = (const float4*)(img + (size_t)b*N_*H_);
  float4 acc = {0.f,0.f,0.f,0.f};
  for (int n=0;n<N_;n++){
    float al = sAl[n];
    float4 x = ib[n*(H_/4) + t];
    acc.x += al*x.x; acc.y += al*x.y; acc.z += al*x.z; acc.w += al*x.w;
  }
  *(float4*)(outCtx + (size_t)b*H_ + t*4) = acc;
}

extern "C" void kernel_launch(void* const* d_in, const int* in_sizes, int n_in,
                              void* d_out, int out_size, void* d_ws, size_t ws_size,
                              hipStream_t stream){
  const float* hidden = (const float*)d_in[0];
  const float* img    = (const float*)d_in[1];
  const float* cov    = (const float*)d_in[2];
  const float* W_h    = (const float*)d_in[3];
  const float* b_h    = (const float*)d_in[4];
  const float* W_img  = (const float*)d_in[5];
  const float* b_img  = (const float*)d_in[6];
  const float* W_cov  = (const float*)d_in[7];
  const float* v      = (const float*)d_in[8];

  char* ws = (char*)d_ws;
  unsigned short* WtH   = (unsigned short*)ws;               // 1 MB
  unsigned short* WtImg = (unsigned short*)(ws + (1u<<20));  // 1 MB
  float* hproj   = (float*)(ws + (2u<<20));                  // 4 MB
  float* scoresP = (float*)(ws + (6u<<20));                  // 2 slabs (0.8 MB) / scores
  unsigned short* imgb = (unsigned short*)(ws + (8u<<20));   // 196 MB

  float* outCtx   = (float*)d_out;
  float* outAlpha = outCtx + (size_t)B_*H_;

  const size_t needed = (8ull<<20) + (size_t)M_*H_*2;

  k_transpose<<<dim3(512, 2), 256, 0, stream>>>(W_h, W_img, WtH, WtImg);
  k_hproj<<<dim3(B_/128, A_/128), 256, 0, stream>>>(hidden, WtH, b_h, hproj);

  if (ws_size >= needed){
    k_convert<<<2048, 256, 0, stream>>>(img, imgb, (size_t)M_*H_/8);
    k_scores_b2p<<<(M_/256)*(A_/256), 512, 0, stream>>>(imgb, WtImg, hproj, b_img, cov, W_cov, v, scoresP);
    k_ctx_b<<<B_, 256, 0, stream>>>(imgb, scoresP, outCtx, outAlpha);
  } else {
    hipMemsetAsync(scoresP, 0, (size_t)M_*sizeof(float), stream);
    k_scores_f<<<dim3(M_/128, A_/128), 256, 0, stream>>>(img, WtImg, hproj, b_img, cov, W_cov, v, scoresP);
    k_ctx_f<<<B_, 256, 0, stream>>>(img, scoresP, outCtx, outAlpha);
  }
}